// Round 5
// baseline (390.924 us; speedup 1.0000x reference)
//
#include <hip/hip_runtime.h>

// LSTM B=4096, T=60, F=128, H=256. Round-12.
// Zero-sync, int8 weights, K=64 i8 MFMA. R11 -> R12: REVERT to the proven
// R7 structure (156us lstm; R8 textual interleave=164, R11 SGB=200 -- all
// interleave attempts measured as serial pipes: MFMA 1600 + VALU 3280 +
// LDS 1400 ~= 6240 cyc/step). New in R12: gate math vectorized to float2
// ext-vectors so clang can emit dual-FP32 VOPP (v_pk_fma_f32/v_pk_mul_f32):
// cells processed in rr-pairs, all elementwise ops 2-wide, exp2/rcp stay
// scalar per component. IEEE-identical math -> absmax unchanged.

#define T_STEPS 60
#define F_DIM 128
#define H_DIM 256
#define BC 16
#define ZQ 31.75f
#define L2E 1.44269504f

typedef __attribute__((ext_vector_type(4))) int intx4;
typedef __attribute__((ext_vector_type(2))) float f32x2;

__device__ __forceinline__ int q8(float v) {
    return __float2int_rn(fminf(fmaxf(v, -127.f), 127.f));
}

// Fused prep. Blocks 0..7: gate g=b>>1, column-half ch=b&1 (max+quant+pack).
// Block 8: head collapse (out = h.vhead + shead).
__global__ __launch_bounds__(1024)
void prep_kernel(const float* __restrict__ Wf, const float* __restrict__ Wu,
                 const float* __restrict__ Wc, const float* __restrict__ Wo,
                 const float* __restrict__ Wd1, const float* __restrict__ bd1,
                 const float* __restrict__ Wd2, const float* __restrict__ bd2,
                 float* __restrict__ cscale, intx4* __restrict__ qpack,
                 float* __restrict__ vhead, float* __restrict__ shead) {
    const int t = threadIdx.x;
    const int b = blockIdx.x;
    if (b < 8) {
        __shared__ float red[16][128];
        __shared__ float fsc[128];
        const int g = b >> 1, ch = b & 1;
        const float* W = (g == 0) ? Wf : (g == 1) ? Wu : (g == 2) ? Wc : Wo;
        const int col = ch * 128 + (t & 127);
        const int grp = t >> 7;                       // 0..7
        float mx = 1e-20f, mh = 1e-20f;
#pragma unroll 4
        for (int i = 0; i < 16; ++i)
            mx = fmaxf(mx, fabsf(W[(size_t)(grp * 16 + i) * H_DIM + col]));
#pragma unroll 4
        for (int i = 0; i < 32; ++i)
            mh = fmaxf(mh, fabsf(W[(size_t)(128 + grp * 32 + i) * H_DIM + col]));
        red[grp][t & 127] = mx;
        red[8 + grp][t & 127] = mh;
        __syncthreads();
        if (t < 128) {
            float Mx = red[0][t], Mh = red[8][t];
#pragma unroll
            for (int i = 1; i < 8; ++i) {
                Mx = fmaxf(Mx, red[i][t]);
                Mh = fmaxf(Mh, red[8 + i][t]);
            }
            float cs = fmaxf(4.f * Mx, Mh) * (1.f / 16129.f);
            cscale[g * 256 + ch * 128 + t] = cs;
            fsc[t] = 1.f / (127.f * cs);
        }
        __syncthreads();
        // pack: 8 hblk x 6 ks6 frags x 64 lanes = 3072 tasks
#pragma unroll
        for (int i = 0; i < 3; ++i) {
            int task = i * 1024 + t;
            int lane = task & 63, fr = task >> 6;     // fr 0..47
            int hl = fr / 6, ks6 = fr - hl * 6;
            int l15 = lane & 15, quad = lane >> 4;
            int colw = ch * 128 + hl * 16 + l15;
            int k0 = ks6 * 64 + quad * 16;
            float f = ((ks6 < 2) ? 4.f : 1.f) * fsc[hl * 16 + l15];
            int w[4];
#pragma unroll
            for (int d = 0; d < 4; ++d) {
                int b0 = q8(W[(size_t)(k0 + d * 4 + 0) * H_DIM + colw] * f) & 255;
                int b1 = q8(W[(size_t)(k0 + d * 4 + 1) * H_DIM + colw] * f) & 255;
                int b2 = q8(W[(size_t)(k0 + d * 4 + 2) * H_DIM + colw] * f) & 255;
                int b3 = q8(W[(size_t)(k0 + d * 4 + 3) * H_DIM + colw] * f) & 255;
                w[d] = b0 | (b1 << 8) | (b2 << 16) | (b3 << 24);
            }
            intx4 v = {w[0], w[1], w[2], w[3]};
            qpack[(((ch * 8 + hl) * 4 + g) * 6 + ks6) * 64 + lane] = v;
        }
    } else {
        __shared__ float hp[1024];
        const int j = t >> 2, q = t & 3;
        float s = 0.f;
        const float* row = Wd1 + (size_t)j * H_DIM + q * 64;
#pragma unroll
        for (int i = 0; i < 16; ++i) {
            float4 a = *(const float4*)(row + i * 4);
            float4 bb = *(const float4*)(Wd2 + q * 64 + i * 4);
            s += a.x * bb.x + a.y * bb.y + a.z * bb.z + a.w * bb.w;
        }
        hp[t] = s;
        __syncthreads();
        float vj = 0.f;
        if (q == 0) vj = hp[t] + hp[t + 1] + hp[t + 2] + hp[t + 3];
        __syncthreads();
        if (q == 0) vhead[j] = vj;
        if (t < 256) hp[t] = bd1[t] * Wd2[t];
        __syncthreads();
        for (int off = 128; off > 0; off >>= 1) {
            if (t < off) hp[t] += hp[t + off];
            __syncthreads();
        }
        if (t == 0) shead[0] = hp[0] + bd2[0];
    }
}

__global__ __launch_bounds__(512)
__attribute__((amdgpu_waves_per_eu(2, 2)))
void lstm_kernel(const float* __restrict__ x,
                 const float* __restrict__ bfv, const float* __restrict__ buv,
                 const float* __restrict__ bcv, const float* __restrict__ bov,
                 const intx4* __restrict__ qpack,
                 const float* __restrict__ cscale,
                 const float* __restrict__ vhead, const float* __restrict__ shead,
                 float* __restrict__ out)
{
    __shared__ __align__(16) intx4 wlds[64 * 64];              // ks6=5 slice, 64 KB
    __shared__ __align__(16) signed char zbuf[2][6][1024];     // double-buffered, 12 KB
    __shared__ float rowsum[BC];

    const int tid  = threadIdx.x;
    const int wave = tid >> 6;
    const int lane = tid & 63;
    const int quad = lane >> 4;
    const int l15  = lane & 15;
    const int b0   = blockIdx.x * BC;

    // ---- stage LDS weight slice (ks6 = 5) ----
    for (int i = tid; i < 64 * 64; i += 512)
        wlds[i] = qpack[((i >> 6) * 6 + 5) * 64 + (i & 63)];
    // ---- register weight slices (ks6 = 0..4), pinned ----
    intx4 wreg[5][8];
#pragma unroll
    for (int j = 0; j < 8; ++j)
#pragma unroll
        for (int ks = 0; ks < 5; ++ks) {
            intx4 v = qpack[(((8 * wave + j) * 6 + ks) * 64) + lane];
            int a0 = v[0], a1 = v[1], a2 = v[2], a3 = v[3];
            asm volatile("" : "+v"(a0), "+v"(a1), "+v"(a2), "+v"(a3));
            intx4 w = {a0, a1, a2, a3};
            wreg[ks][j] = w;
        }

    for (int i = tid; i < 2 * 6 * 1024 / 4; i += 512) ((int*)zbuf)[i] = 0;
    if (tid < BC) rowsum[tid] = 0.f;

    // ---- per-lane cell params (exp2 constants folded into dequant) ----
    float csS[2][4], bS[2][4], vh[2];
    f32x2 creg2[2][2] = {};
    int haddr[2];
#pragma unroll
    for (int hb = 0; hb < 2; ++hb) {
        int a = 2 * wave + hb;
        int hc = a * 16 + l15;
        vh[hb] = vhead[hc];
        haddr[hb] = (2 + (a >> 2)) * 1024 + (a & 3) * 256 + l15;
#pragma unroll
        for (int g = 0; g < 4; ++g) {
            float cs = cscale[g * 256 + hc];
            float bi = (g == 0 ? bfv : g == 1 ? buv : g == 2 ? bcv : bov)[hc];
            float m = (g == 2) ? (-2.f * L2E) : (-L2E);
            csS[hb][g] = m * cs;
            bS[hb][g] = m * bi;
        }
    }

    // ---- x staging addresses ----
    const int xm = tid >> 5, xi = tid & 31;
    const int f0 = xi * 4;
    const int xaddr = (f0 >> 6) * 1024 + ((f0 & 63) >> 4) * 256 + xm * 16 + (f0 & 15);
    const float* xp = x + (size_t)(b0 + xm) * T_STEPS * F_DIM + f0;

    __syncthreads();
    float4 xv = *(const float4*)(xp);
    {
        unsigned u = (unsigned)(q8(xv.x * ZQ) & 255) | ((unsigned)(q8(xv.y * ZQ) & 255) << 8) |
                     ((unsigned)(q8(xv.z * ZQ) & 255) << 16) | ((unsigned)(q8(xv.w * ZQ) & 255) << 24);
        *(unsigned*)(&zbuf[0][0][0] + xaddr) = u;
    }
    xv = *(const float4*)(xp + F_DIM);
    __syncthreads();

    // Paired LSTM cell (rr = 2*rp, 2*rp+1): dequant -> activations (paired
    // rcp) -> c,h update, all as f32x2 so clang can emit v_pk_* VOPP.
    // exp2/rcp are scalar per component (no packed trans on CDNA).
#define GATE_PAIR(hb, rp)                                                          \
    {                                                                              \
        const int R0 = (rp) * 2, R1 = (rp) * 2 + 1;                                \
        const f32x2 one2 = {1.f, 1.f};                                             \
        f32x2 vf = {(float)acc[(hb) * 4 + 0][R0], (float)acc[(hb) * 4 + 0][R1]};   \
        f32x2 vu = {(float)acc[(hb) * 4 + 1][R0], (float)acc[(hb) * 4 + 1][R1]};   \
        f32x2 vc = {(float)acc[(hb) * 4 + 2][R0], (float)acc[(hb) * 4 + 2][R1]};   \
        f32x2 vo = {(float)acc[(hb) * 4 + 3][R0], (float)acc[(hb) * 4 + 3][R1]};   \
        f32x2 uf = __builtin_elementwise_fma(                                      \
            vf, (f32x2){csS[hb][0], csS[hb][0]}, (f32x2){bS[hb][0], bS[hb][0]});   \
        f32x2 uu = __builtin_elementwise_fma(                                      \
            vu, (f32x2){csS[hb][1], csS[hb][1]}, (f32x2){bS[hb][1], bS[hb][1]});   \
        f32x2 uc = __builtin_elementwise_fma(                                      \
            vc, (f32x2){csS[hb][2], csS[hb][2]}, (f32x2){bS[hb][2], bS[hb][2]});   \
        f32x2 uo = __builtin_elementwise_fma(                                      \
            vo, (f32x2){csS[hb][3], csS[hb][3]}, (f32x2){bS[hb][3], bS[hb][3]});   \
        f32x2 af = {__builtin_amdgcn_exp2f(uf.x), __builtin_amdgcn_exp2f(uf.y)};   \
        f32x2 au = {__builtin_amdgcn_exp2f(uu.x), __builtin_amdgcn_exp2f(uu.y)};   \
        f32x2 ac = {__builtin_amdgcn_exp2f(uc.x), __builtin_amdgcn_exp2f(uc.y)};   \
        f32x2 ao = {__builtin_amdgcn_exp2f(uo.x), __builtin_amdgcn_exp2f(uo.y)};   \
        af += one2; au += one2; ac += one2; ao += one2;                            \
        f32x2 p1 = af * au, p2 = ac * ao;                                          \
        f32x2 r1 = {__builtin_amdgcn_rcpf(p1.x), __builtin_amdgcn_rcpf(p1.y)};     \
        f32x2 r2 = {__builtin_amdgcn_rcpf(p2.x), __builtin_amdgcn_rcpf(p2.y)};     \
        f32x2 fg = au * r1;                                                        \
        f32x2 ug = af * r1;                                                        \
        f32x2 rc = ao * r2;                                                        \
        f32x2 og = ac * r2;                                                        \
        f32x2 cn = __builtin_elementwise_fma(                                      \
            fg, creg2[hb][rp], __builtin_elementwise_fma(ug + ug, rc, -ug));       \
        creg2[hb][rp] = cn;                                                        \
        f32x2 ecn = cn * (f32x2){-2.f * L2E, -2.f * L2E};                          \
        f32x2 eh = {__builtin_amdgcn_exp2f(ecn.x), __builtin_amdgcn_exp2f(ecn.y)}; \
        eh += one2;                                                                \
        f32x2 rh = {__builtin_amdgcn_rcpf(eh.x), __builtin_amdgcn_rcpf(eh.y)};     \
        f32x2 hn = __builtin_elementwise_fma(og + og, rh, -og);                    \
        zw[haddr[hb] + (quad * 4 + R0) * 16] =                                     \
            (signed char)__float2int_rn(hn.x * 127.f);                             \
        zw[haddr[hb] + (quad * 4 + R1) * 16] =                                     \
            (signed char)__float2int_rn(hn.y * 127.f);                             \
    }

    for (int t = 0; t < T_STEPS; ++t) {
        const int p = t & 1, pn = p ^ 1;
        const intx4* zr = (const intx4*)(&zbuf[p][0][0]);
        signed char* zw = &zbuf[pn][0][0];

        intx4 acc[8] = {};
#pragma unroll
        for (int ks = 0; ks < 5; ++ks) {
            intx4 a = zr[ks * 64 + lane];
#pragma unroll
            for (int j = 0; j < 8; ++j)
                acc[j] = __builtin_amdgcn_mfma_i32_16x16x64_i8(a, wreg[ks][j], acc[j], 0, 0, 0);
        }
        {
            intx4 a5 = zr[5 * 64 + lane];
#pragma unroll
            for (int j = 0; j < 8; ++j) {
                intx4 bw = wlds[(8 * wave + j) * 64 + lane];
                acc[j] = __builtin_amdgcn_mfma_i32_16x16x64_i8(a5, bw, acc[j], 0, 0, 0);
            }
        }

        if (t < T_STEPS - 1) {
            // stage x_{t+1} into the other buffer
            unsigned u = (unsigned)(q8(xv.x * ZQ) & 255) | ((unsigned)(q8(xv.y * ZQ) & 255) << 8) |
                         ((unsigned)(q8(xv.z * ZQ) & 255) << 16) | ((unsigned)(q8(xv.w * ZQ) & 255) << 24);
            *(unsigned*)(zw + xaddr) = u;
            if (t < T_STEPS - 2)
                xv = *(const float4*)(xp + (size_t)(t + 2) * F_DIM);

#pragma unroll
            for (int hb = 0; hb < 2; ++hb) {
                GATE_PAIR(hb, 0);
                GATE_PAIR(hb, 1);
            }
        } else {
            f32x2 hs2[2] = {};
#pragma unroll
            for (int hb = 0; hb < 2; ++hb)
#pragma unroll
                for (int rp = 0; rp < 2; ++rp) {
                    const int R0 = rp * 2, R1 = rp * 2 + 1;
                    const f32x2 one2 = {1.f, 1.f};
                    f32x2 vf = {(float)acc[hb * 4 + 0][R0], (float)acc[hb * 4 + 0][R1]};
                    f32x2 vu = {(float)acc[hb * 4 + 1][R0], (float)acc[hb * 4 + 1][R1]};
                    f32x2 vc = {(float)acc[hb * 4 + 2][R0], (float)acc[hb * 4 + 2][R1]};
                    f32x2 vo = {(float)acc[hb * 4 + 3][R0], (float)acc[hb * 4 + 3][R1]};
                    f32x2 uf = __builtin_elementwise_fma(
                        vf, (f32x2){csS[hb][0], csS[hb][0]}, (f32x2){bS[hb][0], bS[hb][0]});
                    f32x2 uu = __builtin_elementwise_fma(
                        vu, (f32x2){csS[hb][1], csS[hb][1]}, (f32x2){bS[hb][1], bS[hb][1]});
                    f32x2 uc = __builtin_elementwise_fma(
                        vc, (f32x2){csS[hb][2], csS[hb][2]}, (f32x2){bS[hb][2], bS[hb][2]});
                    f32x2 uo = __builtin_elementwise_fma(
                        vo, (f32x2){csS[hb][3], csS[hb][3]}, (f32x2){bS[hb][3], bS[hb][3]});
                    f32x2 af = {__builtin_amdgcn_exp2f(uf.x), __builtin_amdgcn_exp2f(uf.y)};
                    f32x2 au = {__builtin_amdgcn_exp2f(uu.x), __builtin_amdgcn_exp2f(uu.y)};
                    f32x2 ac = {__builtin_amdgcn_exp2f(uc.x), __builtin_amdgcn_exp2f(uc.y)};
                    f32x2 ao = {__builtin_amdgcn_exp2f(uo.x), __builtin_amdgcn_exp2f(uo.y)};
                    af += one2; au += one2; ac += one2; ao += one2;
                    f32x2 p1 = af * au, p2 = ac * ao;
                    f32x2 r1 = {__builtin_amdgcn_rcpf(p1.x), __builtin_amdgcn_rcpf(p1.y)};
                    f32x2 r2 = {__builtin_amdgcn_rcpf(p2.x), __builtin_amdgcn_rcpf(p2.y)};
                    f32x2 fg = au * r1;
                    f32x2 ug = af * r1;
                    f32x2 rc = ao * r2;
                    f32x2 og = ac * r2;
                    f32x2 cn = __builtin_elementwise_fma(
                        fg, creg2[hb][rp], __builtin_elementwise_fma(ug + ug, rc, -ug));
                    f32x2 ecn = cn * (f32x2){-2.f * L2E, -2.f * L2E};
                    f32x2 eh = {__builtin_amdgcn_exp2f(ecn.x), __builtin_amdgcn_exp2f(ecn.y)};
                    eh += one2;
                    f32x2 rh = {__builtin_amdgcn_rcpf(eh.x), __builtin_amdgcn_rcpf(eh.y)};
                    f32x2 hn = __builtin_elementwise_fma(og + og, rh, -og);
                    hs2[rp] += hn * (f32x2){vh[hb], vh[hb]};
                }
#pragma unroll
            for (int rr = 0; rr < 4; ++rr) {
                float s = (rr & 1) ? hs2[rr >> 1].y : hs2[rr >> 1].x;
#pragma unroll
                for (int m = 1; m < 16; m <<= 1)
                    s += __shfl_xor(s, m, 64);
                if (l15 == 0)
                    atomicAdd(&rowsum[quad * 4 + rr], s);
            }
        }
        __syncthreads();
    }
#undef GATE_PAIR

    if (tid < BC)
        out[b0 + tid] = rowsum[tid] + shead[0];
}

extern "C" void kernel_launch(void* const* d_in, const int* in_sizes, int n_in,
                              void* d_out, int out_size, void* d_ws, size_t ws_size,
                              hipStream_t stream) {
    (void)in_sizes; (void)n_in; (void)out_size; (void)ws_size;
    const float* x   = (const float*)d_in[0];
    const float* Wf  = (const float*)d_in[1];
    const float* bfv = (const float*)d_in[2];
    const float* Wu  = (const float*)d_in[3];
    const float* buv = (const float*)d_in[4];
    const float* Wc  = (const float*)d_in[5];
    const float* bcv = (const float*)d_in[6];
    const float* Wo  = (const float*)d_in[7];
    const float* bov = (const float*)d_in[8];
    const float* Wd1 = (const float*)d_in[9];
    const float* bd1 = (const float*)d_in[10];
    const float* Wd2 = (const float*)d_in[11];
    const float* bd2 = (const float*)d_in[12];

    char* ws = (char*)d_ws;
    intx4* qpack = (intx4*)ws;                               // 384 KB
    size_t off = (size_t)384 * 64 * 16;
    float* cscale = (float*)(ws + off); off += 1024 * 4;
    float* vhead  = (float*)(ws + off); off += 256 * 4;
    float* shead  = (float*)(ws + off); off += 16;

    prep_kernel<<<9, 1024, 0, stream>>>(Wf, Wu, Wc, Wo, Wd1, bd1, Wd2, bd2,
                                        cscale, qpack, vhead, shead);
    lstm_kernel<<<256, 512, 0, stream>>>(x, bfv, buv, bcv, bov, qpack, cscale,
                                         vhead, shead, (float*)d_out);
}

// Round 6
// 334.147 us; speedup vs baseline: 1.1699x; 1.1699x over previous
//
#include <hip/hip_runtime.h>

// LSTM B=4096, T=60, F=128, H=256. Round-13.
// Zero-sync, int8 weights, K=64 i8 MFMA. R12 (f32x2, 237us: scratch-bound,
// WRITE_SIZE 22MB) reverted. Base = R7 structure (best: 156us lstm / 306 total).
// Changes vs R7 (step-loop math untouched):
//  - x PRE-QUANTIZED in prep (x has no recurrence dependence): qx int8 tensor,
//    bit-identical q8(x*ZQ) pack. lstm staging = load u32 + ds_write (removes
//    ~23 VALU ops/thread/step + float4 load; x FETCH 126MB -> 31.5MB).
//    Guarded by ws_size >= 32MB; fallback = exact R7 path (templated).
//  - prep gate-pack parallelism 8 -> 32 blocks (4x finer col split; fmax is
//    exact-associative so results bit-identical); x-quant runs on 512 extra
//    blocks concurrently in the SAME prep launch (prep was 9 blocks on a
//    256-CU chip -- probing whether prep is part of the fixed ~150us gap).

#define T_STEPS 60
#define F_DIM 128
#define H_DIM 256
#define B_DIM 4096
#define BC 16
#define ZQ 31.75f
#define L2E 1.44269504f

typedef __attribute__((ext_vector_type(4))) int intx4;

__device__ __forceinline__ int q8(float v) {
    return __float2int_rn(fminf(fmaxf(v, -127.f), 127.f));
}

// Fused prep.
//  blocks 0..31 : gate g=b>>3, column-half ch=(b>>2)&1, quarter qtr=b&3
//                 (max+quant+pack for 32 columns each).
//  block 32     : head collapse (out = h.vhead + shead).
//  blocks 33+   : x pre-quantization (grid-stride over all of x).
__global__ __launch_bounds__(1024)
void prep_kernel(const float* __restrict__ Wf, const float* __restrict__ Wu,
                 const float* __restrict__ Wc, const float* __restrict__ Wo,
                 const float* __restrict__ Wd1, const float* __restrict__ bd1,
                 const float* __restrict__ Wd2, const float* __restrict__ bd2,
                 float* __restrict__ cscale, intx4* __restrict__ qpack,
                 float* __restrict__ vhead, float* __restrict__ shead,
                 const float* __restrict__ x, unsigned* __restrict__ qx) {
    const int t = threadIdx.x;
    const int b = blockIdx.x;
    if (b < 32) {
        __shared__ float red[64][32];
        __shared__ float fsc[32];
        const int g = b >> 3, ch = (b >> 2) & 1, qtr = b & 3;
        const float* W = (g == 0) ? Wf : (g == 1) ? Wu : (g == 2) ? Wc : Wo;
        const int c32 = t & 31;
        const int col = ch * 128 + qtr * 32 + c32;
        const int grp = t >> 5;                       // 0..31
        float mx = 1e-20f, mh = 1e-20f;
#pragma unroll
        for (int i = 0; i < 4; ++i)
            mx = fmaxf(mx, fabsf(W[(size_t)(grp * 4 + i) * H_DIM + col]));
#pragma unroll
        for (int i = 0; i < 8; ++i)
            mh = fmaxf(mh, fabsf(W[(size_t)(128 + grp * 8 + i) * H_DIM + col]));
        red[grp][c32] = mx;
        red[32 + grp][c32] = mh;
        __syncthreads();
        if (t < 32) {
            float Mx = red[0][t], Mh = red[32][t];
#pragma unroll 8
            for (int i = 1; i < 32; ++i) {
                Mx = fmaxf(Mx, red[i][t]);
                Mh = fmaxf(Mh, red[32 + i][t]);
            }
            float cs = fmaxf(4.f * Mx, Mh) * (1.f / 16129.f);
            cscale[g * 256 + ch * 128 + qtr * 32 + t] = cs;
            fsc[t] = 1.f / (127.f * cs);
        }
        __syncthreads();
        // pack: 2 hl x 6 ks6 x 64 lanes = 768 tasks
        if (t < 768) {
            int lane = t & 63, fr = t >> 6;           // fr 0..11
            int hli = fr / 6, ks6 = fr - hli * 6;
            int hl = qtr * 2 + hli;
            int l15 = lane & 15, quad = lane >> 4;
            int colw = ch * 128 + hl * 16 + l15;
            int k0 = ks6 * 64 + quad * 16;
            float f = ((ks6 < 2) ? 4.f : 1.f) * fsc[hli * 16 + l15];
            int w[4];
#pragma unroll
            for (int d = 0; d < 4; ++d) {
                int b0 = q8(W[(size_t)(k0 + d * 4 + 0) * H_DIM + colw] * f) & 255;
                int b1 = q8(W[(size_t)(k0 + d * 4 + 1) * H_DIM + colw] * f) & 255;
                int b2 = q8(W[(size_t)(k0 + d * 4 + 2) * H_DIM + colw] * f) & 255;
                int b3 = q8(W[(size_t)(k0 + d * 4 + 3) * H_DIM + colw] * f) & 255;
                w[d] = b0 | (b1 << 8) | (b2 << 16) | (b3 << 24);
            }
            intx4 v = {w[0], w[1], w[2], w[3]};
            qpack[(((ch * 8 + hl) * 4 + g) * 6 + ks6) * 64 + lane] = v;
        }
    } else if (b == 32) {
        __shared__ float hp[1024];
        const int j = t >> 2, q = t & 3;
        float s = 0.f;
        const float* row = Wd1 + (size_t)j * H_DIM + q * 64;
#pragma unroll
        for (int i = 0; i < 16; ++i) {
            float4 a = *(const float4*)(row + i * 4);
            float4 bb = *(const float4*)(Wd2 + q * 64 + i * 4);
            s += a.x * bb.x + a.y * bb.y + a.z * bb.z + a.w * bb.w;
        }
        hp[t] = s;
        __syncthreads();
        float vj = 0.f;
        if (q == 0) vj = hp[t] + hp[t + 1] + hp[t + 2] + hp[t + 3];
        __syncthreads();
        if (q == 0) vhead[j] = vj;
        if (t < 256) hp[t] = bd1[t] * Wd2[t];
        __syncthreads();
        for (int off = 128; off > 0; off >>= 1) {
            if (t < off) hp[t] += hp[t + off];
            __syncthreads();
        }
        if (t == 0) shead[0] = hp[0] + bd2[0];
    } else {
        // x pre-quantization: word w holds bytes q8(x[4w..4w+3]*ZQ)
        const size_t NW = (size_t)B_DIM * T_STEPS * (F_DIM / 4);
        const size_t stride = (size_t)(gridDim.x - 33) * 1024;
        for (size_t w = (size_t)(b - 33) * 1024 + t; w < NW; w += stride) {
            float4 v = *(const float4*)(x + w * 4);
            unsigned u = (unsigned)(q8(v.x * ZQ) & 255) |
                         ((unsigned)(q8(v.y * ZQ) & 255) << 8) |
                         ((unsigned)(q8(v.z * ZQ) & 255) << 16) |
                         ((unsigned)(q8(v.w * ZQ) & 255) << 24);
            qx[w] = u;
        }
    }
}

template <bool USE_QX>
__global__ __launch_bounds__(512)
__attribute__((amdgpu_waves_per_eu(2, 2)))
void lstm_kernel(const float* __restrict__ x,
                 const float* __restrict__ bfv, const float* __restrict__ buv,
                 const float* __restrict__ bcv, const float* __restrict__ bov,
                 const intx4* __restrict__ qpack,
                 const float* __restrict__ cscale,
                 const float* __restrict__ vhead, const float* __restrict__ shead,
                 const unsigned* __restrict__ qx,
                 float* __restrict__ out)
{
    __shared__ __align__(16) intx4 wlds[64 * 64];              // ks6=5 slice, 64 KB
    __shared__ __align__(16) signed char zbuf[2][6][1024];     // double-buffered, 12 KB
    __shared__ float rowsum[BC];

    const int tid  = threadIdx.x;
    const int wave = tid >> 6;
    const int lane = tid & 63;
    const int quad = lane >> 4;
    const int l15  = lane & 15;
    const int b0   = blockIdx.x * BC;

    // ---- stage LDS weight slice (ks6 = 5) ----
    for (int i = tid; i < 64 * 64; i += 512)
        wlds[i] = qpack[((i >> 6) * 6 + 5) * 64 + (i & 63)];
    // ---- register weight slices (ks6 = 0..4), pinned ----
    intx4 wreg[5][8];
#pragma unroll
    for (int j = 0; j < 8; ++j)
#pragma unroll
        for (int ks = 0; ks < 5; ++ks) {
            intx4 v = qpack[(((8 * wave + j) * 6 + ks) * 64) + lane];
            int a0 = v[0], a1 = v[1], a2 = v[2], a3 = v[3];
            asm volatile("" : "+v"(a0), "+v"(a1), "+v"(a2), "+v"(a3));
            intx4 w = {a0, a1, a2, a3};
            wreg[ks][j] = w;
        }

    for (int i = tid; i < 2 * 6 * 1024 / 4; i += 512) ((int*)zbuf)[i] = 0;
    if (tid < BC) rowsum[tid] = 0.f;

    // ---- per-lane cell params (exp2 constants folded into dequant) ----
    float csS[2][4], bS[2][4], vh[2];
    float creg[2][4] = {};
    int haddr[2];
#pragma unroll
    for (int hb = 0; hb < 2; ++hb) {
        int a = 2 * wave + hb;
        int hc = a * 16 + l15;
        vh[hb] = vhead[hc];
        haddr[hb] = (2 + (a >> 2)) * 1024 + (a & 3) * 256 + l15;
#pragma unroll
        for (int g = 0; g < 4; ++g) {
            float cs = cscale[g * 256 + hc];
            float bi = (g == 0 ? bfv : g == 1 ? buv : g == 2 ? bcv : bov)[hc];
            float m = (g == 2) ? (-2.f * L2E) : (-L2E);
            csS[hb][g] = m * cs;
            bS[hb][g] = m * bi;
        }
    }

    // ---- x staging addresses ----
    const int xm = tid >> 5, xi = tid & 31;
    const int f0 = xi * 4;
    const int xaddr = (f0 >> 6) * 1024 + ((f0 & 63) >> 4) * 256 + xm * 16 + (f0 & 15);
    const float* xp = x + (size_t)(b0 + xm) * T_STEPS * F_DIM + f0;
    const unsigned* qxp = qx + (size_t)(b0 + xm) * T_STEPS * (F_DIM / 4) + xi;

    __syncthreads();
    float4 xv;
    unsigned xu;
    if constexpr (USE_QX) {
        unsigned u0 = qxp[0];
        *(unsigned*)(&zbuf[0][0][0] + xaddr) = u0;
        xu = qxp[32];                                   // x_{t=1}
    } else {
        xv = *(const float4*)(xp);
        unsigned u = (unsigned)(q8(xv.x * ZQ) & 255) | ((unsigned)(q8(xv.y * ZQ) & 255) << 8) |
                     ((unsigned)(q8(xv.z * ZQ) & 255) << 16) | ((unsigned)(q8(xv.w * ZQ) & 255) << 24);
        *(unsigned*)(&zbuf[0][0][0] + xaddr) = u;
        xv = *(const float4*)(xp + F_DIM);
    }
    __syncthreads();

    // One LSTM cell: dequant 4 gates -> activations (paired rcp) -> c,h update
    // -> quantize h byte into the other z-buffer.
#define GATE_CELL(hb, rr)                                                          \
    {                                                                              \
        float uf = fmaf((float)acc[(hb) * 4 + 0][rr], csS[hb][0], bS[hb][0]);      \
        float uu = fmaf((float)acc[(hb) * 4 + 1][rr], csS[hb][1], bS[hb][1]);      \
        float uc = fmaf((float)acc[(hb) * 4 + 2][rr], csS[hb][2], bS[hb][2]);      \
        float uo = fmaf((float)acc[(hb) * 4 + 3][rr], csS[hb][3], bS[hb][3]);      \
        float af = 1.f + __builtin_amdgcn_exp2f(uf);                               \
        float au = 1.f + __builtin_amdgcn_exp2f(uu);                               \
        float ac = 1.f + __builtin_amdgcn_exp2f(uc);                               \
        float ao = 1.f + __builtin_amdgcn_exp2f(uo);                               \
        float r1 = __builtin_amdgcn_rcpf(af * au);                                 \
        float r2 = __builtin_amdgcn_rcpf(ac * ao);                                 \
        float fg = au * r1;                                                        \
        float ug = af * r1;                                                        \
        float rc = ao * r2;                                                        \
        float og = ac * r2;                                                        \
        float cn = fmaf(fg, creg[hb][rr], fmaf(ug + ug, rc, -ug));                 \
        creg[hb][rr] = cn;                                                         \
        float rh = __builtin_amdgcn_rcpf(1.f + __builtin_amdgcn_exp2f(cn * (-2.f * L2E))); \
        float hn = fmaf(og + og, rh, -og);                                         \
        zw[haddr[hb] + (quad * 4 + (rr)) * 16] =                                   \
            (signed char)__float2int_rn(hn * 127.f);                               \
    }

    for (int t = 0; t < T_STEPS; ++t) {
        const int p = t & 1, pn = p ^ 1;
        const intx4* zr = (const intx4*)(&zbuf[p][0][0]);
        signed char* zw = &zbuf[pn][0][0];

        intx4 acc[8] = {};
#pragma unroll
        for (int ks = 0; ks < 5; ++ks) {
            intx4 a = zr[ks * 64 + lane];
#pragma unroll
            for (int j = 0; j < 8; ++j)
                acc[j] = __builtin_amdgcn_mfma_i32_16x16x64_i8(a, wreg[ks][j], acc[j], 0, 0, 0);
        }
        {
            intx4 a5 = zr[5 * 64 + lane];
#pragma unroll
            for (int j = 0; j < 8; ++j) {
                intx4 bw = wlds[(8 * wave + j) * 64 + lane];
                acc[j] = __builtin_amdgcn_mfma_i32_16x16x64_i8(a5, bw, acc[j], 0, 0, 0);
            }
        }

        if (t < T_STEPS - 1) {
            // stage x_{t+1} into the other buffer
            if constexpr (USE_QX) {
                *(unsigned*)(zw + xaddr) = xu;
                if (t < T_STEPS - 2)
                    xu = qxp[(size_t)(t + 2) * 32];
            } else {
                unsigned u = (unsigned)(q8(xv.x * ZQ) & 255) | ((unsigned)(q8(xv.y * ZQ) & 255) << 8) |
                             ((unsigned)(q8(xv.z * ZQ) & 255) << 16) | ((unsigned)(q8(xv.w * ZQ) & 255) << 24);
                *(unsigned*)(zw + xaddr) = u;
                if (t < T_STEPS - 2)
                    xv = *(const float4*)(xp + (size_t)(t + 2) * F_DIM);
            }

#pragma unroll
            for (int hb = 0; hb < 2; ++hb)
#pragma unroll
                for (int rr = 0; rr < 4; ++rr)
                    GATE_CELL(hb, rr);
        } else {
            float hs[4] = {0.f, 0.f, 0.f, 0.f};
#pragma unroll
            for (int hb = 0; hb < 2; ++hb)
#pragma unroll
                for (int rr = 0; rr < 4; ++rr) {
                    float uf = fmaf((float)acc[hb * 4 + 0][rr], csS[hb][0], bS[hb][0]);
                    float uu = fmaf((float)acc[hb * 4 + 1][rr], csS[hb][1], bS[hb][1]);
                    float uc = fmaf((float)acc[hb * 4 + 2][rr], csS[hb][2], bS[hb][2]);
                    float uo = fmaf((float)acc[hb * 4 + 3][rr], csS[hb][3], bS[hb][3]);
                    float af = 1.f + __builtin_amdgcn_exp2f(uf);
                    float au = 1.f + __builtin_amdgcn_exp2f(uu);
                    float ac = 1.f + __builtin_amdgcn_exp2f(uc);
                    float ao = 1.f + __builtin_amdgcn_exp2f(uo);
                    float r1 = __builtin_amdgcn_rcpf(af * au);
                    float r2 = __builtin_amdgcn_rcpf(ac * ao);
                    float fg = au * r1;
                    float ug = af * r1;
                    float rc = ao * r2;
                    float og = ac * r2;
                    float cn = fmaf(fg, creg[hb][rr], fmaf(ug + ug, rc, -ug));
                    float rh = __builtin_amdgcn_rcpf(1.f + __builtin_amdgcn_exp2f(cn * (-2.f * L2E)));
                    float hn = fmaf(og + og, rh, -og);
                    hs[rr] += hn * vh[hb];
                }
#pragma unroll
            for (int rr = 0; rr < 4; ++rr) {
                float s = hs[rr];
#pragma unroll
                for (int m = 1; m < 16; m <<= 1)
                    s += __shfl_xor(s, m, 64);
                if (l15 == 0)
                    atomicAdd(&rowsum[quad * 4 + rr], s);
            }
        }
        __syncthreads();
    }
#undef GATE_CELL

    if (tid < BC)
        out[b0 + tid] = rowsum[tid] + shead[0];
}

extern "C" void kernel_launch(void* const* d_in, const int* in_sizes, int n_in,
                              void* d_out, int out_size, void* d_ws, size_t ws_size,
                              hipStream_t stream) {
    (void)in_sizes; (void)n_in; (void)out_size;
    const float* x   = (const float*)d_in[0];
    const float* Wf  = (const float*)d_in[1];
    const float* bfv = (const float*)d_in[2];
    const float* Wu  = (const float*)d_in[3];
    const float* buv = (const float*)d_in[4];
    const float* Wc  = (const float*)d_in[5];
    const float* bcv = (const float*)d_in[6];
    const float* Wo  = (const float*)d_in[7];
    const float* bov = (const float*)d_in[8];
    const float* Wd1 = (const float*)d_in[9];
    const float* bd1 = (const float*)d_in[10];
    const float* Wd2 = (const float*)d_in[11];
    const float* bd2 = (const float*)d_in[12];

    char* ws = (char*)d_ws;
    intx4* qpack = (intx4*)ws;                               // 384 KB
    size_t off = (size_t)384 * 64 * 16;
    float* cscale = (float*)(ws + off); off += 1024 * 4;
    float* vhead  = (float*)(ws + off); off += 256 * 4;
    float* shead  = (float*)(ws + off); off += 16;
    unsigned* qx  = (unsigned*)(ws + off);
    const size_t qx_bytes = (size_t)B_DIM * T_STEPS * (F_DIM / 4) * 4;  // 31.5 MB
    const bool use_qx = ws_size >= off + qx_bytes;

    prep_kernel<<<use_qx ? 545 : 33, 1024, 0, stream>>>(
        Wf, Wu, Wc, Wo, Wd1, bd1, Wd2, bd2, cscale, qpack, vhead, shead, x, qx);
    if (use_qx)
        lstm_kernel<true><<<256, 512, 0, stream>>>(x, bfv, buv, bcv, bov, qpack,
                                                   cscale, vhead, shead, qx,
                                                   (float*)d_out);
    else
        lstm_kernel<false><<<256, 512, 0, stream>>>(x, bfv, buv, bcv, bov, qpack,
                                                    cscale, vhead, shead, qx,
                                                    (float*)d_out);
}